// Round 23
// baseline (135.178 us; speedup 1.0000x reference)
//
#include <hip/hip_runtime.h>
#include <stdint.h>

typedef unsigned short u16;
typedef __attribute__((ext_vector_type(8))) __bf16 bf16x8;
typedef __attribute__((ext_vector_type(4))) float f32x4;
typedef __attribute__((ext_vector_type(4))) unsigned short u16x4;

__device__ __forceinline__ float bf2f(u16 u){
  unsigned int x = ((unsigned int)u) << 16;
  return __builtin_bit_cast(float, x);
}
__device__ __forceinline__ u16 f2bf(float f){
  return __builtin_bit_cast(u16, (__bf16)f);
}
__device__ __forceinline__ float fexp2(float x){ return __builtin_exp2f(x); }
__device__ __forceinline__ void lds_load16(const void* g, void* l){
  __builtin_amdgcn_global_load_lds(
      (const __attribute__((address_space(1))) unsigned int*)g,
      (__attribute__((address_space(3))) unsigned int*)l, 16, 0, 0);
}

// ------- fused prep: transpose w_qkv, transpose w_out, convert x -------------
__device__ __forceinline__ void transpose_body(const float* __restrict__ in,
                                               u16* __restrict__ out,
                                               int R, int C, int bx, int by,
                                               u16 (*t)[65]){
  const int c0 = bx * 64, r0 = by * 64;
  const int tid = threadIdx.x;
  const int rr = tid >> 3;
  const int cc = (tid & 7) * 8;
#pragma unroll
  for (int i = 0; i < 2; i++){
    int r = i * 32 + rr;
    const float* p = in + (size_t)(r0 + r) * C + c0 + cc;
    f32x4 v0 = *(const f32x4*)p;
    f32x4 v1 = *(const f32x4*)(p + 4);
#pragma unroll
    for (int j = 0; j < 4; j++){ t[r][cc + j] = f2bf(v0[j]); t[r][cc + 4 + j] = f2bf(v1[j]); }
  }
  __syncthreads();
#pragma unroll
  for (int i = 0; i < 2; i++){
    int c = i * 32 + rr;
    u16 tmp[8];
#pragma unroll
    for (int j = 0; j < 8; j++) tmp[j] = t[cc + j][c];
    *(bf16x8*)(out + (size_t)(c0 + c) * R + r0 + cc) = *(const bf16x8*)tmp;
  }
}

__global__ __launch_bounds__(256) void prep(const float* __restrict__ w_qkv,
                                            const float* __restrict__ w_out,
                                            const float* __restrict__ x,
                                            u16* __restrict__ wT1,
                                            u16* __restrict__ wT2,
                                            u16* __restrict__ xbf){
  __shared__ u16 t[64][65];
  const int bid = blockIdx.x;
  if (bid < 2048){
    int i = bid * 256 + threadIdx.x;
    const float* p = x + (size_t)i * 8;
    f32x4 v0 = *(const f32x4*)p;
    f32x4 v1 = *(const f32x4*)(p + 4);
    u16 tmp[8];
#pragma unroll
    for (int j = 0; j < 4; j++){ tmp[j] = f2bf(v0[j]); tmp[4 + j] = f2bf(v1[j]); }
    *(bf16x8*)(xbf + (size_t)i * 8) = *(const bf16x8*)tmp;
  } else if (bid < 2048 + 768){
    int idx = bid - 2048;
    transpose_body(w_qkv, wT1, 1024, 3072, idx % 48, idx / 48, t);
  } else {
    int idx = bid - 2816;
    transpose_body(w_out, wT2, 1024, 1024, idx % 16, idx / 16, t);
  }
}

// ------- vT[bh][d=64][s=2048] = V third of qkv, per-head transposed ----------
__global__ __launch_bounds__(256) void v_transpose(const u16* __restrict__ qkv,
                                                   u16* __restrict__ vT){
  const int S = 2048, LD = 3072;
  __shared__ u16 t[64][65];
  const int bh = blockIdx.y;
  const int b = bh >> 4, h = bh & 15;
  const int s0 = blockIdx.x * 64;
  const u16* src = qkv + (size_t)b * S * LD + 2048 + h * 64;
  const int tid = threadIdx.x;
  const int rr = tid >> 3;
  const int cc = (tid & 7) * 8;
#pragma unroll
  for (int i = 0; i < 2; i++){
    int s = i * 32 + rr;
    bf16x8 v = *(const bf16x8*)(src + (size_t)(s0 + s) * LD + cc);
#pragma unroll
    for (int j = 0; j < 8; j++) t[s][cc + j] = __builtin_bit_cast(u16, (__bf16)v[j]);
  }
  __syncthreads();
  u16* dst = vT + (size_t)bh * 64 * S;
#pragma unroll
  for (int i = 0; i < 2; i++){
    int d = i * 32 + rr;
    u16 tmp[8];
#pragma unroll
    for (int j = 0; j < 8; j++) tmp[j] = t[cc + j][d];
    *(bf16x8*)(dst + (size_t)d * S + s0 + cc) = *(const bf16x8*)tmp;
  }
}

// -------- GEMM: BK=32, DMA staging + XCD swizzle, 3 blocks/CU ----------------
template<bool OUTF32, bool ROPE>
__global__ __launch_bounds__(256, 3) void gemm_bt(const u16* __restrict__ A,
                                                  const u16* __restrict__ Bt,
                                                  const float* __restrict__ bias,
                                                  void* __restrict__ Cv,
                                                  int M, int N, int K,
                                                  const float* __restrict__ cosb,
                                                  const float* __restrict__ sinb){
  __shared__ u16 As[128 * 32];
  __shared__ u16 Bs[128 * 32];
  const int nx = gridDim.x;
  const int L = blockIdx.x + nx * blockIdx.y;
  const int per = (nx * gridDim.y) >> 3;
  const int wg = (L & 7) * per + (L >> 3);
  const int bn = wg % nx, bm = wg / nx;
  const int tid = threadIdx.x, w = tid >> 6, l = tid & 63;
  const int lo = l & 15, hi = l >> 4;
  const int wr = (w >> 1) * 64, wc = (w & 1) * 64;
  f32x4 acc[4][4] = {};
  const int lrow = l >> 2, lcd = l & 3;

  for (int k0 = 0; k0 < K; k0 += 32){
#pragma unroll
    for (int i = 0; i < 2; i++){
      int row0 = i * 64 + w * 16;
      int row = row0 + lrow;
      int cs = lcd ^ ((row >> 1) & 3);
      lds_load16(A  + (size_t)(bm * 128 + row) * K + k0 + cs * 8,
                 (char*)As + row0 * 64);
      lds_load16(Bt + (size_t)(bn * 128 + row) * K + k0 + cs * 8,
                 (char*)Bs + row0 * 64);
    }
    __syncthreads();
    bf16x8 a[4], b[4];
#pragma unroll
    for (int mi = 0; mi < 4; mi++){
      int row = wr + mi * 16 + lo;
      unsigned byte = (unsigned)(row * 64 + hi * 16) ^ (((row >> 1) & 3) << 4);
      a[mi] = *(const bf16x8*)((const char*)As + byte);
    }
#pragma unroll
    for (int ni = 0; ni < 4; ni++){
      int row = wc + ni * 16 + lo;
      unsigned byte = (unsigned)(row * 64 + hi * 16) ^ (((row >> 1) & 3) << 4);
      b[ni] = *(const bf16x8*)((const char*)Bs + byte);
    }
    __builtin_amdgcn_s_setprio(1);
#pragma unroll
    for (int mi = 0; mi < 4; mi++)
#pragma unroll
      for (int ni = 0; ni < 4; ni++)
        acc[mi][ni] = __builtin_amdgcn_mfma_f32_16x16x32_bf16(a[mi], b[ni], acc[mi][ni], 0, 0, 0);
    __builtin_amdgcn_s_setprio(0);
    __syncthreads();
  }
  if (ROPE && bn < 16){
#pragma unroll
    for (int mi = 0; mi < 4; mi++){
#pragma unroll
      for (int r = 0; r < 4; r++){
        int grow = bm * 128 + wr + mi * 16 + hi * 4 + r;
        int stok = grow & 2047;
#pragma unroll
        for (int ni = 0; ni < 4; ni++){
          int col = bn * 128 + wc + ni * 16 + lo;
          float v = acc[mi][ni][r] + bias[col];
          float partner = __shfl_xor(v, 1, 64);
          int ip = (col & 63) >> 1;
          float c = cosb[stok * 32 + ip], sn = sinb[stok * 32 + ip];
          float res = (lo & 1) ? (partner * sn + v * c) : (v * c - partner * sn);
          ((u16*)Cv)[(size_t)grow * N + col] = f2bf(res);
        }
      }
    }
  } else {
#pragma unroll
    for (int mi = 0; mi < 4; mi++){
#pragma unroll
      for (int r = 0; r < 4; r++){
        int grow = bm * 128 + wr + mi * 16 + hi * 4 + r;
#pragma unroll
        for (int ni = 0; ni < 4; ni++){
          int col = bn * 128 + wc + ni * 16 + lo;
          float v = acc[mi][ni][r] + bias[col];
          if (OUTF32)
            ((float*)Cv)[(size_t)grow * N + col] = v;
          else
            ((u16*)Cv)[(size_t)grow * N + col] = f2bf(v);
        }
      }
    }
  }
}

// ---- flash attention: 64-row tile/block, 4 subtiles/iter, 2-wave split-K ----
// Grid 1024: bh = L & 31 (XCD-pinned), T = 31 - (L>>5) heavy-first.
// Per 32-key iteration: one K stage + one V load feed FOUR 16-row subtiles
// (2x the work of r20's iteration -> amortizes fixed chain latency, per r18).
// kt == 2T+1 fully masks subtiles A,B -> wave-uniform skip (partials merge to
// zero weight via m=-1e30). LDS 35.3 KB -> 4 blocks/CU, 2 waves/SIMD.
#define PM8(sa) fmaxf(fmaxf(fmaxf(sa[0][0], sa[0][1]), fmaxf(sa[0][2], sa[0][3])), \
                      fmaxf(fmaxf(sa[1][0], sa[1][1]), fmaxf(sa[1][2], sa[1][3])))

#define FA_RESC(X) { \
    float rm = fmaxf(pm##X, __shfl_xor(pm##X, 16, 64)); \
    rm = fmaxf(rm, __shfl_xor(rm, 32, 64)); \
    float mn = fmaxf(m##X, rm); \
    float cc = fexp2(m##X - mn); \
    m##X = mn; lp##X *= cc; \
    float cq[4]; \
    _Pragma("unroll") for (int r = 0; r < 4; r++) cq[r] = __shfl(cc, hi * 4 + r, 64); \
    _Pragma("unroll") for (int fd = 0; fd < 4; fd++){ \
      _Pragma("unroll") for (int r = 0; r < 4; r++) o##X[fd][r] *= cq[r]; } }

#define FA_SMPV(X, PSI) { \
    float pv0[4], pv1[4]; \
    _Pragma("unroll") for (int r = 0; r < 4; r++){ \
      pv0[r] = fexp2(sa##X[0][r] - m##X); pv1[r] = fexp2(sa##X[1][r] - m##X); } \
    u16x4 pk0, pk1; \
    _Pragma("unroll") for (int r = 0; r < 4; r++){ pk0[r] = f2bf(pv0[r]); pk1[r] = f2bf(pv1[r]); } \
    *(u16x4*)((char*)&Ps[w][PSI][0] + lo * 72 + hi * 8) = pk0; \
    *(u16x4*)((char*)&Ps[w][PSI][0] + lo * 72 + 32 + hi * 8) = pk1; \
    lp##X += ((pv0[0] + pv0[1]) + (pv0[2] + pv0[3])) \
           + ((pv1[0] + pv1[1]) + (pv1[2] + pv1[3])); \
    bf16x8 pa = *(const bf16x8*)((const char*)&Ps[w][PSI][0] + lo * 72 + hi * 16); \
    __builtin_amdgcn_s_setprio(1); \
    _Pragma("unroll") for (int fd = 0; fd < 4; fd++) \
      o##X[fd] = __builtin_amdgcn_mfma_f32_16x16x32_bf16(pa, vb[fd], o##X[fd], 0, 0, 0); \
    __builtin_amdgcn_s_setprio(0); }

#define FA_COMB(X, SUB) { \
    u16x4 p_[4]; \
    _Pragma("unroll") for (int fd = 0; fd < 4; fd++) \
      p_[fd] = *(const u16x4*)((const char*)Xo + (fd * 16 + lo) * 144 + (SUB) * 32 + hi * 8); \
    _Pragma("unroll") for (int r = 0; r < 4; r++){ \
      float mO = __shfl(m##X, hi * 4 + r, 64); \
      float lO = __shfl(lp##X, hi * 4 + r, 64); \
      float mP = Xm[(SUB) * 16 + hi * 4 + r], lP = Xl[(SUB) * 16 + hi * 4 + r]; \
      float Mf = fmaxf(mO, mP); \
      float c0 = fexp2(mO - Mf), c1 = fexp2(mP - Mf); \
      float inv = 1.0f / (lO * c0 + lP * c1); \
      int sr = q0 + (SUB) * 16 + hi * 4 + r; \
      u16* orow = Oout + (size_t)(b * S + sr) * 1024 + h * 64; \
      _Pragma("unroll") for (int fd = 0; fd < 4; fd++) \
        orow[fd * 16 + lo] = f2bf((o##X[fd][r] * c0 + bf2f(p_[fd][r]) * c1) * inv); } }

__global__ __launch_bounds__(128, 2) void flash_attn(const u16* __restrict__ qkv,
                                                     const u16* __restrict__ vT,
                                                     u16* __restrict__ Oout){
  const int S = 2048, LD = 3072;
  const int L = blockIdx.x;
  const int bh = L & 31;
  const int T = 31 - (L >> 5);
  const int b = bh >> 4, h = bh & 15;
  const u16* base = qkv + (size_t)b * S * LD;
  const u16* Qp = base + h * 64;
  const u16* Kp = base + 1024 + h * 64;
  const u16* Vb = vT + (size_t)bh * 64 * S;
  const int tid = threadIdx.x, w = tid >> 6, l = tid & 63;
  const int lo = l & 15, hi = l >> 4;
  __shared__ u16 Ks[2][2][32 * 64];         // [wave][buf] K dbuf (DMA)
  __shared__ u16 Ps[2][4][16 * 36];         // [wave][subtile] P roundtrip
  __shared__ u16 Xo[64 * 72];               // partial O exchange, 144B rows
  __shared__ float Xm[64], Xl[64];

  const float QSC = 0.125f * 1.44269504089f;
  const int srow8 = l >> 3;
  const int scs = (l & 7) ^ srow8;

  const int q0 = T * 64;
  const int qrA = q0 + lo,      qrB = q0 + 16 + lo;
  const int qrC = q0 + 32 + lo, qrD = q0 + 48 + lo;
  const int nkt2 = 2 * T + 2;
  const int ch = T + 1;
  const int k0 = w ? ch : 0;
  const int k1 = w ? nkt2 : ch;

  bf16x8 qfA0, qfA1, qfB0, qfB1, qfC0, qfC1, qfD0, qfD1;
#define LOADQ(X, QR) { \
    bf16x8 v0 = *(const bf16x8*)(Qp + (size_t)(QR) * LD + hi * 8); \
    bf16x8 v1 = *(const bf16x8*)(Qp + (size_t)(QR) * LD + 32 + hi * 8); \
    _Pragma("unroll") for (int j = 0; j < 8; j++){ \
      qf##X##0[j] = (__bf16)((float)v0[j] * QSC); \
      qf##X##1[j] = (__bf16)((float)v1[j] * QSC); } }
  LOADQ(A, qrA); LOADQ(B, qrB); LOADQ(C, qrC); LOADQ(D, qrD);

  f32x4 oA[4] = {}, oB[4] = {}, oC[4] = {}, oD[4] = {};
  float mA = -1e30f, mB = -1e30f, mC = -1e30f, mD = -1e30f;
  float lpA = 0.f, lpB = 0.f, lpC = 0.f, lpD = 0.f;

  // prologue: stage first K tile
#pragma unroll
  for (int i = 0; i < 4; i++)
    lds_load16(Kp + (size_t)(k0 * 32 + i * 8 + srow8) * LD + scs * 8,
               (char*)&Ks[w][0][0] + i * 1024);

  int cur = 0;
  for (int kt = k0; kt < k1; kt++){
    bf16x8 vb[4];
#pragma unroll
    for (int fd = 0; fd < 4; fd++)
      vb[fd] = *(const bf16x8*)(Vb + (size_t)(fd * 16 + lo) * S + kt * 32 + hi * 8);
    bf16x8 kb[2][2];
#pragma unroll
    for (int c = 0; c < 2; c++)
#pragma unroll
      for (int f = 0; f < 2; f++){
        int srw = f * 16 + lo;
        unsigned byte = ((unsigned)(srw * 128 + c * 64 + hi * 16)) ^ ((lo & 7) << 4);
        kb[c][f] = *(const bf16x8*)((const char*)&Ks[w][cur][0] + byte);
      }
    if (kt + 1 < k1){
#pragma unroll
      for (int i = 0; i < 4; i++)
        lds_load16(Kp + (size_t)((kt + 1) * 32 + i * 8 + srow8) * LD + scs * 8,
                   (char*)&Ks[w][cur ^ 1][0] + i * 1024);
    }
    const bool doAB = (kt != 2 * T + 1);   // kt==2T+1 fully masks A,B
    f32x4 saA[2] = {}, saB[2] = {}, saC[2] = {}, saD[2] = {};
    __builtin_amdgcn_s_setprio(1);
    if (doAB){
#pragma unroll
      for (int f = 0; f < 2; f++){
        saA[f] = __builtin_amdgcn_mfma_f32_16x16x32_bf16(kb[0][f], qfA0, saA[f], 0, 0, 0);
        saB[f] = __builtin_amdgcn_mfma_f32_16x16x32_bf16(kb[0][f], qfB0, saB[f], 0, 0, 0);
        saA[f] = __builtin_amdgcn_mfma_f32_16x16x32_bf16(kb[1][f], qfA1, saA[f], 0, 0, 0);
        saB[f] = __builtin_amdgcn_mfma_f32_16x16x32_bf16(kb[1][f], qfB1, saB[f], 0, 0, 0);
      }
    }
#pragma unroll
    for (int f = 0; f < 2; f++){
      saC[f] = __builtin_amdgcn_mfma_f32_16x16x32_bf16(kb[0][f], qfC0, saC[f], 0, 0, 0);
      saD[f] = __builtin_amdgcn_mfma_f32_16x16x32_bf16(kb[0][f], qfD0, saD[f], 0, 0, 0);
      saC[f] = __builtin_amdgcn_mfma_f32_16x16x32_bf16(kb[1][f], qfC1, saC[f], 0, 0, 0);
      saD[f] = __builtin_amdgcn_mfma_f32_16x16x32_bf16(kb[1][f], qfD1, saD[f], 0, 0, 0);
    }
    __builtin_amdgcn_s_setprio(0);
    if (kt >= 2 * T){                       // only last two K-tiles cross diag
#pragma unroll
      for (int f = 0; f < 2; f++){
        int key0 = kt * 32 + f * 16 + hi * 4;
#pragma unroll
        for (int r = 0; r < 4; r++){
          if (key0 + r > qrA) saA[f][r] = -1e30f;
          if (key0 + r > qrB) saB[f][r] = -1e30f;
          if (key0 + r > qrC) saC[f][r] = -1e30f;
          if (key0 + r > qrD) saD[f][r] = -1e30f;
        }
      }
    }
    float pmA = doAB ? PM8(saA) : mA;
    float pmB = doAB ? PM8(saB) : mB;
    float pmC = PM8(saC), pmD = PM8(saD);
    float dm = fmaxf(fmaxf(pmA - mA, pmB - mB), fmaxf(pmC - mC, pmD - mD));
    if (!__all(dm <= 11.5f)){
      FA_RESC(A); FA_RESC(B); FA_RESC(C); FA_RESC(D);
    }
    if (doAB){ FA_SMPV(A, 0); FA_SMPV(B, 1); }
    FA_SMPV(C, 2); FA_SMPV(D, 3);
    cur ^= 1;
  }
  // row-sum partials
  lpA += __shfl_xor(lpA, 16, 64); lpA += __shfl_xor(lpA, 32, 64);
  lpB += __shfl_xor(lpB, 16, 64); lpB += __shfl_xor(lpB, 32, 64);
  lpC += __shfl_xor(lpC, 16, 64); lpC += __shfl_xor(lpC, 32, 64);
  lpD += __shfl_xor(lpD, 16, 64); lpD += __shfl_xor(lpD, 32, 64);

  __syncthreads();
  if (w == 1){
#pragma unroll
    for (int fd = 0; fd < 4; fd++){
      u16x4 pkA, pkB, pkC, pkD;
#pragma unroll
      for (int r = 0; r < 4; r++){
        pkA[r] = f2bf(oA[fd][r]); pkB[r] = f2bf(oB[fd][r]);
        pkC[r] = f2bf(oC[fd][r]); pkD[r] = f2bf(oD[fd][r]);
      }
      char* rowp = (char*)Xo + (fd * 16 + lo) * 144 + hi * 8;
      *(u16x4*)(rowp)      = pkA;
      *(u16x4*)(rowp + 32) = pkB;
      *(u16x4*)(rowp + 64) = pkC;
      *(u16x4*)(rowp + 96) = pkD;
    }
    if (hi == 0){
      Xm[lo] = mA;      Xl[lo] = lpA;
      Xm[16 + lo] = mB; Xl[16 + lo] = lpB;
      Xm[32 + lo] = mC; Xl[32 + lo] = lpC;
      Xm[48 + lo] = mD; Xl[48 + lo] = lpD;
    }
  }
  __syncthreads();
  if (w == 0){
    FA_COMB(A, 0); FA_COMB(B, 1); FA_COMB(C, 2); FA_COMB(D, 3);
  }
}

extern "C" void kernel_launch(void* const* d_in, const int* in_sizes, int n_in,
                              void* d_out, int out_size, void* d_ws, size_t ws_size,
                              hipStream_t stream){
  const float* x     = (const float*)d_in[0];
  const float* w_qkv = (const float*)d_in[1];
  const float* b_qkv = (const float*)d_in[2];
  const float* w_out = (const float*)d_in[3];
  const float* b_out = (const float*)d_in[4];
  const float* cosb  = (const float*)d_in[5];
  const float* sinb  = (const float*)d_in[6];
  // d_in[7] = mask: causal, implemented analytically.
  float* out = (float*)d_out;
  char* ws = (char*)d_ws;
  u16* qkv  = (u16*)(ws);               // bf16 [4096][3072]   25.2 MB
  u16* attn = (u16*)(ws + 25165824);    // bf16 [4096][1024]    8.4 MB
  u16* xbf  = attn;                     // x bf16 — dead before flash writes attn
  u16* wT2  = (u16*)(ws + 33554432);    // w_out^T bf16 [1024][1024]  2.1 MB
  u16* wT1  = (u16*)(ws + 35651584);    // w_qkv^T bf16 [3072][1024]  6.3 MB
  u16* vT   = (u16*)(ws + 35651584);    // vT — overlaps wT1 (dead after GEMM1)

  prep<<<3072, 256, 0, stream>>>(w_qkv, w_out, x, wT1, wT2, xbf);
  gemm_bt<false, true ><<<dim3(24, 32), 256, 0, stream>>>(xbf, wT1, b_qkv, qkv,
                                                          4096, 3072, 1024, cosb, sinb);
  v_transpose<<<dim3(32, 32), 256, 0, stream>>>(qkv, vT);
  flash_attn<<<1024, 128, 0, stream>>>(qkv, vT, attn);
  gemm_bt<true , false><<<dim3(8, 32), 256, 0, stream>>>(attn, wT2, b_out, out,
                                                         4096, 1024, 1024, cosb, sinb);
}

// Round 24
// 124.186 us; speedup vs baseline: 1.0885x; 1.0885x over previous
//
#include <hip/hip_runtime.h>
#include <stdint.h>

typedef unsigned short u16;
typedef __attribute__((ext_vector_type(8))) __bf16 bf16x8;
typedef __attribute__((ext_vector_type(4))) float f32x4;
typedef __attribute__((ext_vector_type(4))) unsigned short u16x4;

__device__ __forceinline__ float bf2f(u16 u){
  unsigned int x = ((unsigned int)u) << 16;
  return __builtin_bit_cast(float, x);
}
__device__ __forceinline__ u16 f2bf(float f){
  return __builtin_bit_cast(u16, (__bf16)f);
}
__device__ __forceinline__ float fexp2(float x){ return __builtin_exp2f(x); }
__device__ __forceinline__ void lds_load16(const void* g, void* l){
  __builtin_amdgcn_global_load_lds(
      (const __attribute__((address_space(1))) unsigned int*)g,
      (__attribute__((address_space(3))) unsigned int*)l, 16, 0, 0);
}

// ------- fused prep: transpose w_qkv, transpose w_out, convert x -------------
__device__ __forceinline__ void transpose_body(const float* __restrict__ in,
                                               u16* __restrict__ out,
                                               int R, int C, int bx, int by,
                                               u16 (*t)[65]){
  const int c0 = bx * 64, r0 = by * 64;
  const int tid = threadIdx.x;
  const int rr = tid >> 3;
  const int cc = (tid & 7) * 8;
#pragma unroll
  for (int i = 0; i < 2; i++){
    int r = i * 32 + rr;
    const float* p = in + (size_t)(r0 + r) * C + c0 + cc;
    f32x4 v0 = *(const f32x4*)p;
    f32x4 v1 = *(const f32x4*)(p + 4);
#pragma unroll
    for (int j = 0; j < 4; j++){ t[r][cc + j] = f2bf(v0[j]); t[r][cc + 4 + j] = f2bf(v1[j]); }
  }
  __syncthreads();
#pragma unroll
  for (int i = 0; i < 2; i++){
    int c = i * 32 + rr;
    u16 tmp[8];
#pragma unroll
    for (int j = 0; j < 8; j++) tmp[j] = t[cc + j][c];
    *(bf16x8*)(out + (size_t)(c0 + c) * R + r0 + cc) = *(const bf16x8*)tmp;
  }
}

__global__ __launch_bounds__(256) void prep(const float* __restrict__ w_qkv,
                                            const float* __restrict__ w_out,
                                            const float* __restrict__ x,
                                            u16* __restrict__ wT1,
                                            u16* __restrict__ wT2,
                                            u16* __restrict__ xbf){
  __shared__ u16 t[64][65];
  const int bid = blockIdx.x;
  if (bid < 2048){
    int i = bid * 256 + threadIdx.x;
    const float* p = x + (size_t)i * 8;
    f32x4 v0 = *(const f32x4*)p;
    f32x4 v1 = *(const f32x4*)(p + 4);
    u16 tmp[8];
#pragma unroll
    for (int j = 0; j < 4; j++){ tmp[j] = f2bf(v0[j]); tmp[4 + j] = f2bf(v1[j]); }
    *(bf16x8*)(xbf + (size_t)i * 8) = *(const bf16x8*)tmp;
  } else if (bid < 2048 + 768){
    int idx = bid - 2048;
    transpose_body(w_qkv, wT1, 1024, 3072, idx % 48, idx / 48, t);
  } else {
    int idx = bid - 2816;
    transpose_body(w_out, wT2, 1024, 1024, idx % 16, idx / 16, t);
  }
}

// ------- vT[bh][d=64][s=2048] = V third of qkv, per-head transposed ----------
__global__ __launch_bounds__(256) void v_transpose(const u16* __restrict__ qkv,
                                                   u16* __restrict__ vT){
  const int S = 2048, LD = 3072;
  __shared__ u16 t[64][65];
  const int bh = blockIdx.y;
  const int b = bh >> 4, h = bh & 15;
  const int s0 = blockIdx.x * 64;
  const u16* src = qkv + (size_t)b * S * LD + 2048 + h * 64;
  const int tid = threadIdx.x;
  const int rr = tid >> 3;
  const int cc = (tid & 7) * 8;
#pragma unroll
  for (int i = 0; i < 2; i++){
    int s = i * 32 + rr;
    bf16x8 v = *(const bf16x8*)(src + (size_t)(s0 + s) * LD + cc);
#pragma unroll
    for (int j = 0; j < 8; j++) t[s][cc + j] = __builtin_bit_cast(u16, (__bf16)v[j]);
  }
  __syncthreads();
  u16* dst = vT + (size_t)bh * 64 * S;
#pragma unroll
  for (int i = 0; i < 2; i++){
    int d = i * 32 + rr;
    u16 tmp[8];
#pragma unroll
    for (int j = 0; j < 8; j++) tmp[j] = t[cc + j][d];
    *(bf16x8*)(dst + (size_t)d * S + s0 + cc) = *(const bf16x8*)tmp;
  }
}

// -------- GEMM: BK=32, DMA staging + XCD swizzle, 3 blocks/CU ----------------
template<bool OUTF32, bool ROPE>
__global__ __launch_bounds__(256, 3) void gemm_bt(const u16* __restrict__ A,
                                                  const u16* __restrict__ Bt,
                                                  const float* __restrict__ bias,
                                                  void* __restrict__ Cv,
                                                  int M, int N, int K,
                                                  const float* __restrict__ cosb,
                                                  const float* __restrict__ sinb){
  __shared__ u16 As[128 * 32];
  __shared__ u16 Bs[128 * 32];
  const int nx = gridDim.x;
  const int L = blockIdx.x + nx * blockIdx.y;
  const int per = (nx * gridDim.y) >> 3;
  const int wg = (L & 7) * per + (L >> 3);
  const int bn = wg % nx, bm = wg / nx;
  const int tid = threadIdx.x, w = tid >> 6, l = tid & 63;
  const int lo = l & 15, hi = l >> 4;
  const int wr = (w >> 1) * 64, wc = (w & 1) * 64;
  f32x4 acc[4][4] = {};
  const int lrow = l >> 2, lcd = l & 3;

  for (int k0 = 0; k0 < K; k0 += 32){
#pragma unroll
    for (int i = 0; i < 2; i++){
      int row0 = i * 64 + w * 16;
      int row = row0 + lrow;
      int cs = lcd ^ ((row >> 1) & 3);
      lds_load16(A  + (size_t)(bm * 128 + row) * K + k0 + cs * 8,
                 (char*)As + row0 * 64);
      lds_load16(Bt + (size_t)(bn * 128 + row) * K + k0 + cs * 8,
                 (char*)Bs + row0 * 64);
    }
    __syncthreads();
    bf16x8 a[4], b[4];
#pragma unroll
    for (int mi = 0; mi < 4; mi++){
      int row = wr + mi * 16 + lo;
      unsigned byte = (unsigned)(row * 64 + hi * 16) ^ (((row >> 1) & 3) << 4);
      a[mi] = *(const bf16x8*)((const char*)As + byte);
    }
#pragma unroll
    for (int ni = 0; ni < 4; ni++){
      int row = wc + ni * 16 + lo;
      unsigned byte = (unsigned)(row * 64 + hi * 16) ^ (((row >> 1) & 3) << 4);
      b[ni] = *(const bf16x8*)((const char*)Bs + byte);
    }
    __builtin_amdgcn_s_setprio(1);
#pragma unroll
    for (int mi = 0; mi < 4; mi++)
#pragma unroll
      for (int ni = 0; ni < 4; ni++)
        acc[mi][ni] = __builtin_amdgcn_mfma_f32_16x16x32_bf16(a[mi], b[ni], acc[mi][ni], 0, 0, 0);
    __builtin_amdgcn_s_setprio(0);
    __syncthreads();
  }
  if (ROPE && bn < 16){
#pragma unroll
    for (int mi = 0; mi < 4; mi++){
#pragma unroll
      for (int r = 0; r < 4; r++){
        int grow = bm * 128 + wr + mi * 16 + hi * 4 + r;
        int stok = grow & 2047;
#pragma unroll
        for (int ni = 0; ni < 4; ni++){
          int col = bn * 128 + wc + ni * 16 + lo;
          float v = acc[mi][ni][r] + bias[col];
          float partner = __shfl_xor(v, 1, 64);
          int ip = (col & 63) >> 1;
          float c = cosb[stok * 32 + ip], sn = sinb[stok * 32 + ip];
          float res = (lo & 1) ? (partner * sn + v * c) : (v * c - partner * sn);
          ((u16*)Cv)[(size_t)grow * N + col] = f2bf(res);
        }
      }
    }
  } else {
#pragma unroll
    for (int mi = 0; mi < 4; mi++){
#pragma unroll
      for (int r = 0; r < 4; r++){
        int grow = bm * 128 + wr + mi * 16 + hi * 4 + r;
#pragma unroll
        for (int ni = 0; ni < 4; ni++){
          int col = bn * 128 + wc + ni * 16 + lo;
          float v = acc[mi][ni][r] + bias[col];
          if (OUTF32)
            ((float*)Cv)[(size_t)grow * N + col] = v;
          else
            ((u16*)Cv)[(size_t)grow * N + col] = f2bf(v);
        }
      }
    }
  }
}

// ---- flash attention: r20 structure + K-fragment register prefetch ----------
// Per body: ds_read NEXT tile's K frags into the alternate named set (kbA/kbB,
// manual 2x unroll -> static indices); QK uses the CURRENT set whose lgkm wait
// retired an iteration ago (K LDS latency off the chain). sched_barrier(0)
// pins the kt+2 DMA stage after QK (whose wait proves the overwritten
// buffer's reads retired) -> no DMA-vs-ds_read race.
#define FA_DSREAD(KB_, KT_)                                                    \
  { _Pragma("unroll")                                                          \
    for (int c = 0; c < 2; c++){                                               \
      _Pragma("unroll")                                                        \
      for (int f = 0; f < 2; f++){                                             \
        int srw = f * 16 + lo;                                                 \
        unsigned byte = ((unsigned)(srw * 128 + c * 64 + hi * 16)) ^           \
                        ((lo & 7) << 4);                                       \
        KB_[c * 2 + f] = *(const bf16x8*)(                                     \
            (const char*)&Ks[w][(KT_) & 1][0] + byte);                         \
      } } }

#define FA_STAGE(KT_)                                                          \
  { _Pragma("unroll")                                                          \
    for (int i = 0; i < 4; i++)                                                \
      lds_load16(Kp + (size_t)((KT_) * 32 + i * 8 + srow8) * LD + scs * 8,     \
                 (char*)&Ks[w][(KT_) & 1][0] + i * 1024); }

#define FA_BODY(KBU_, KBL_, KT_, OA_, OB_, MA_, MB_)                           \
  {                                                                            \
    bf16x8 vb[4];                                                              \
    _Pragma("unroll")                                                          \
    for (int fd = 0; fd < 4; fd++)                                             \
      vb[fd] = *(const bf16x8*)(Vb + (size_t)(fd * 16 + lo) * S +              \
                                (KT_) * 32 + hi * 8);                          \
    if ((KT_) + 1 < k1) FA_DSREAD(KBL_, (KT_) + 1);                            \
    f32x4 saA[2] = {}, saB[2] = {};                                            \
    __builtin_amdgcn_s_setprio(1);                                             \
    saA[0] = __builtin_amdgcn_mfma_f32_16x16x32_bf16(KBU_[0], qfA0, saA[0], 0, 0, 0); \
    saB[0] = __builtin_amdgcn_mfma_f32_16x16x32_bf16(KBU_[0], qfB0, saB[0], 0, 0, 0); \
    saA[0] = __builtin_amdgcn_mfma_f32_16x16x32_bf16(KBU_[2], qfA1, saA[0], 0, 0, 0); \
    saB[0] = __builtin_amdgcn_mfma_f32_16x16x32_bf16(KBU_[2], qfB1, saB[0], 0, 0, 0); \
    saA[1] = __builtin_amdgcn_mfma_f32_16x16x32_bf16(KBU_[1], qfA0, saA[1], 0, 0, 0); \
    saB[1] = __builtin_amdgcn_mfma_f32_16x16x32_bf16(KBU_[1], qfB0, saB[1], 0, 0, 0); \
    saA[1] = __builtin_amdgcn_mfma_f32_16x16x32_bf16(KBU_[3], qfA1, saA[1], 0, 0, 0); \
    saB[1] = __builtin_amdgcn_mfma_f32_16x16x32_bf16(KBU_[3], qfB1, saB[1], 0, 0, 0); \
    __builtin_amdgcn_s_setprio(0);                                             \
    __builtin_amdgcn_sched_barrier(0);                                         \
    if ((KT_) + 2 < k1) FA_STAGE((KT_) + 2);                                   \
    if ((KT_) == nkt - 1){                                                     \
      _Pragma("unroll")                                                        \
      for (int f = 0; f < 2; f++){                                             \
        int key0 = (KT_) * 32 + f * 16 + hi * 4;                               \
        _Pragma("unroll")                                                      \
        for (int r = 0; r < 4; r++){                                           \
          if (key0 + r > qrA) saA[f][r] = -1e30f;                              \
          if (key0 + r > qrB) saB[f][r] = -1e30f;                              \
        }                                                                      \
      }                                                                        \
    }                                                                          \
    float pmA = fmaxf(                                                         \
        fmaxf(fmaxf(saA[0][0], saA[0][1]), fmaxf(saA[0][2], saA[0][3])),       \
        fmaxf(fmaxf(saA[1][0], saA[1][1]), fmaxf(saA[1][2], saA[1][3])));      \
    float pmB = fmaxf(                                                         \
        fmaxf(fmaxf(saB[0][0], saB[0][1]), fmaxf(saB[0][2], saB[0][3])),       \
        fmaxf(fmaxf(saB[1][0], saB[1][1]), fmaxf(saB[1][2], saB[1][3])));      \
    if (!__all(fmaxf(pmA - MA_, pmB - MB_) <= 11.5f)){                         \
      float rmA = fmaxf(pmA, __shfl_xor(pmA, 16, 64));                         \
      rmA = fmaxf(rmA, __shfl_xor(rmA, 32, 64));                               \
      float rmB = fmaxf(pmB, __shfl_xor(pmB, 16, 64));                         \
      rmB = fmaxf(rmB, __shfl_xor(rmB, 32, 64));                               \
      float mnA = fmaxf(MA_, rmA), mnB = fmaxf(MB_, rmB);                      \
      float cA = fexp2(MA_ - mnA), cB = fexp2(MB_ - mnB);                      \
      MA_ = mnA; MB_ = mnB;                                                    \
      lparA *= cA; lparB *= cB;                                                \
      float cqA[4], cqB[4];                                                    \
      _Pragma("unroll")                                                        \
      for (int r = 0; r < 4; r++){                                             \
        cqA[r] = __shfl(cA, hi * 4 + r, 64);                                   \
        cqB[r] = __shfl(cB, hi * 4 + r, 64);                                   \
      }                                                                        \
      _Pragma("unroll")                                                        \
      for (int fd = 0; fd < 4; fd++){                                          \
        _Pragma("unroll")                                                      \
        for (int r = 0; r < 4; r++){                                           \
          OA_[fd][r] *= cqA[r]; OB_[fd][r] *= cqB[r];                          \
        }                                                                      \
      }                                                                        \
    }                                                                          \
    float pvA[2][4], pvB[2][4];                                                \
    _Pragma("unroll")                                                          \
    for (int f = 0; f < 2; f++){                                               \
      _Pragma("unroll")                                                        \
      for (int r = 0; r < 4; r++){                                             \
        pvA[f][r] = fexp2(saA[f][r] - MA_);                                    \
        pvB[f][r] = fexp2(saB[f][r] - MB_);                                    \
      }                                                                        \
    }                                                                          \
    _Pragma("unroll")                                                          \
    for (int f = 0; f < 2; f++){                                               \
      u16x4 pkA, pkB;                                                          \
      _Pragma("unroll")                                                        \
      for (int r = 0; r < 4; r++){                                             \
        pkA[r] = f2bf(pvA[f][r]); pkB[r] = f2bf(pvB[f][r]);                    \
      }                                                                        \
      *(u16x4*)((char*)&Ps[w][0][0] + lo * 72 + f * 32 + hi * 8) = pkA;        \
      *(u16x4*)((char*)&Ps[w][1][0] + lo * 72 + f * 32 + hi * 8) = pkB;        \
    }                                                                          \
    lparA += ((pvA[0][0] + pvA[0][1]) + (pvA[0][2] + pvA[0][3]))               \
           + ((pvA[1][0] + pvA[1][1]) + (pvA[1][2] + pvA[1][3]));              \
    lparB += ((pvB[0][0] + pvB[0][1]) + (pvB[0][2] + pvB[0][3]))               \
           + ((pvB[1][0] + pvB[1][1]) + (pvB[1][2] + pvB[1][3]));              \
    bf16x8 paA = *(const bf16x8*)((const char*)&Ps[w][0][0] + lo * 72 +        \
                                  hi * 16);                                    \
    bf16x8 paB = *(const bf16x8*)((const char*)&Ps[w][1][0] + lo * 72 +        \
                                  hi * 16);                                    \
    __builtin_amdgcn_s_setprio(1);                                             \
    _Pragma("unroll")                                                          \
    for (int fd = 0; fd < 4; fd++){                                            \
      OA_[fd] = __builtin_amdgcn_mfma_f32_16x16x32_bf16(paA, vb[fd],           \
                                                        OA_[fd], 0, 0, 0);     \
      OB_[fd] = __builtin_amdgcn_mfma_f32_16x16x32_bf16(paB, vb[fd],           \
                                                        OB_[fd], 0, 0, 0);     \
    }                                                                          \
    __builtin_amdgcn_s_setprio(0);                                             \
  }

#define FA_PHASE(T_, OA_, OB_, MA_, MB_, LA_, LB_)                             \
  {                                                                            \
    const int q0p = (T_) * 32;                                                 \
    const int qrA = q0p + lo, qrB = q0p + 16 + lo;                             \
    const int nkt = (T_) + 1;                                                  \
    const int ch = (nkt + 1) >> 1;                                             \
    const int k0 = w ? ch : 0;                                                 \
    const int k1 = w ? nkt : ch;                                               \
    bf16x8 qfA0, qfA1, qfB0, qfB1;                                             \
    {                                                                          \
      bf16x8 va0 = *(const bf16x8*)(Qp + (size_t)qrA * LD + hi * 8);           \
      bf16x8 va1 = *(const bf16x8*)(Qp + (size_t)qrA * LD + 32 + hi * 8);      \
      bf16x8 vb0 = *(const bf16x8*)(Qp + (size_t)qrB * LD + hi * 8);           \
      bf16x8 vb1 = *(const bf16x8*)(Qp + (size_t)qrB * LD + 32 + hi * 8);      \
      _Pragma("unroll")                                                        \
      for (int j = 0; j < 8; j++){                                             \
        qfA0[j] = (__bf16)((float)va0[j] * QSC);                               \
        qfA1[j] = (__bf16)((float)va1[j] * QSC);                               \
        qfB0[j] = (__bf16)((float)vb0[j] * QSC);                               \
        qfB1[j] = (__bf16)((float)vb1[j] * QSC);                               \
      }                                                                        \
    }                                                                          \
    float lparA = 0.f, lparB = 0.f;                                            \
    MA_ = -1e30f; MB_ = -1e30f;                                                \
    bf16x8 kbA[4], kbB[4];                                                     \
    int kt = k0;                                                               \
    if (kt < k1){                                                              \
      FA_STAGE(kt);                                                            \
      if (kt + 1 < k1) FA_STAGE(kt + 1);                                       \
      FA_DSREAD(kbA, kt);                                                      \
      while (true){                                                            \
        FA_BODY(kbA, kbB, kt, OA_, OB_, MA_, MB_);                             \
        kt++;                                                                  \
        if (kt >= k1) break;                                                   \
        FA_BODY(kbB, kbA, kt, OA_, OB_, MA_, MB_);                             \
        kt++;                                                                  \
        if (kt >= k1) break;                                                   \
      }                                                                        \
    }                                                                          \
    lparA += __shfl_xor(lparA, 16, 64); lparA += __shfl_xor(lparA, 32, 64);    \
    lparB += __shfl_xor(lparB, 16, 64); lparB += __shfl_xor(lparB, 32, 64);    \
    LA_ = lparA; LB_ = lparB;                                                  \
  }

#define FA_WRITEPART(slot_, OA_, OB_, MA_, MB_, LA_, LB_)                      \
  {                                                                            \
    _Pragma("unroll")                                                          \
    for (int fd = 0; fd < 4; fd++){                                            \
      u16x4 pkA, pkB;                                                          \
      _Pragma("unroll")                                                        \
      for (int r = 0; r < 4; r++){                                             \
        pkA[r] = f2bf(OA_[fd][r]); pkB[r] = f2bf(OB_[fd][r]);                  \
      }                                                                        \
      *(u16x4*)((char*)&Xo[slot_][0] + (fd * 16 + lo) * 72 + hi * 8) = pkA;    \
      *(u16x4*)((char*)&Xo[slot_][0] + (fd * 16 + lo) * 72 + 32 + hi * 8) = pkB;\
    }                                                                          \
    if (hi == 0){                                                              \
      Xm[slot_][lo] = MA_;      Xl[slot_][lo] = LA_;                           \
      Xm[slot_][16 + lo] = MB_; Xl[slot_][16 + lo] = LB_;                      \
    }                                                                          \
  }

#define FA_COMBINE(slot_, T_, OA_, OB_, MA_, MB_, LA_, LB_)                    \
  {                                                                            \
    const int q0p = (T_) * 32;                                                 \
    u16x4 pA[4], pB[4];                                                        \
    _Pragma("unroll")                                                          \
    for (int fd = 0; fd < 4; fd++){                                            \
      pA[fd] = *(const u16x4*)((const char*)&Xo[slot_][0] +                    \
                               (fd * 16 + lo) * 72 + hi * 8);                  \
      pB[fd] = *(const u16x4*)((const char*)&Xo[slot_][0] +                    \
                               (fd * 16 + lo) * 72 + 32 + hi * 8);             \
    }                                                                          \
    _Pragma("unroll")                                                          \
    for (int r = 0; r < 4; r++){                                               \
      float mOA = __shfl(MA_, hi * 4 + r, 64);                                 \
      float lOA = __shfl(LA_, hi * 4 + r, 64);                                 \
      float mOB = __shfl(MB_, hi * 4 + r, 64);                                 \
      float lOB = __shfl(LB_, hi * 4 + r, 64);                                 \
      float mPA = Xm[slot_][hi * 4 + r], lPA = Xl[slot_][hi * 4 + r];          \
      float mPB = Xm[slot_][16 + hi * 4 + r], lPB = Xl[slot_][16 + hi * 4 + r];\
      float MfA = fmaxf(mOA, mPA), MfB = fmaxf(mOB, mPB);                      \
      float c0A = fexp2(mOA - MfA), c1A = fexp2(mPA - MfA);                    \
      float c0B = fexp2(mOB - MfB), c1B = fexp2(mPB - MfB);                    \
      float invA = 1.0f / (lOA * c0A + lPA * c1A);                             \
      float invB = 1.0f / (lOB * c0B + lPB * c1B);                             \
      int srA = q0p + hi * 4 + r;                                              \
      int srB = q0p + 16 + hi * 4 + r;                                         \
      u16* orA = Oout + (size_t)(b * S + srA) * 1024 + h * 64;                 \
      u16* orB = Oout + (size_t)(b * S + srB) * 1024 + h * 64;                 \
      _Pragma("unroll")                                                        \
      for (int fd = 0; fd < 4; fd++){                                          \
        float vA = (OA_[fd][r] * c0A + bf2f(pA[fd][r]) * c1A) * invA;          \
        float vB = (OB_[fd][r] * c0B + bf2f(pB[fd][r]) * c1B) * invB;          \
        orA[fd * 16 + lo] = f2bf(vA);                                          \
        orB[fd * 16 + lo] = f2bf(vB);                                          \
      }                                                                        \
    }                                                                          \
  }

__global__ __launch_bounds__(128, 2) void flash_attn(const u16* __restrict__ qkv,
                                                     const u16* __restrict__ vT,
                                                     u16* __restrict__ Oout){
  const int S = 2048, LD = 3072;
  const int L = blockIdx.x;
  const int bh = L & 31;
  const int bx = L >> 5;                    // 0..31
  const int b = bh >> 4, h = bh & 15;
  const u16* base = qkv + (size_t)b * S * LD;
  const u16* Qp = base + h * 64;
  const u16* Kp = base + 1024 + h * 64;
  const u16* Vb = vT + (size_t)bh * 64 * S;
  const int tid = threadIdx.x, w = tid >> 6, l = tid & 63;
  const int lo = l & 15, hi = l >> 4;
  __shared__ u16 Ks[2][2][32 * 64];         // [wave][buf]
  __shared__ u16 Ps[2][2][16 * 36];         // [wave][subtile]
  __shared__ u16 Xo[2][64 * 36];            // [slot] partial O, 72B rows
  __shared__ float Xm[2][32], Xl[2][32];

  const float QSC = 0.125f * 1.44269504089f;
  const int srow8 = l >> 3;
  const int scs = (l & 7) ^ srow8;

  f32x4 o1A[4] = {}, o1B[4] = {};           // phase1 (T0) partial
  f32x4 o2A[4] = {}, o2B[4] = {};           // phase2 (T1) partial
  float m1A, m1B, l1A, l1B, m2A, m2B, l2A, l2B;

  FA_PHASE(63 - bx, o1A, o1B, m1A, m1B, l1A, l1B);
  if (w == 1) FA_WRITEPART(0, o1A, o1B, m1A, m1B, l1A, l1B);
  FA_PHASE(bx,      o2A, o2B, m2A, m2B, l2A, l2B);
  if (w == 0) FA_WRITEPART(1, o2A, o2B, m2A, m2B, l2A, l2B);
  __syncthreads();
  if (w == 0){
    FA_COMBINE(0, 63 - bx, o1A, o1B, m1A, m1B, l1A, l1B);
  } else {
    FA_COMBINE(1, bx,      o2A, o2B, m2A, m2B, l2A, l2B);
  }
}

extern "C" void kernel_launch(void* const* d_in, const int* in_sizes, int n_in,
                              void* d_out, int out_size, void* d_ws, size_t ws_size,
                              hipStream_t stream){
  const float* x     = (const float*)d_in[0];
  const float* w_qkv = (const float*)d_in[1];
  const float* b_qkv = (const float*)d_in[2];
  const float* w_out = (const float*)d_in[3];
  const float* b_out = (const float*)d_in[4];
  const float* cosb  = (const float*)d_in[5];
  const float* sinb  = (const float*)d_in[6];
  // d_in[7] = mask: causal, implemented analytically.
  float* out = (float*)d_out;
  char* ws = (char*)d_ws;
  u16* qkv  = (u16*)(ws);               // bf16 [4096][3072]   25.2 MB
  u16* attn = (u16*)(ws + 25165824);    // bf16 [4096][1024]    8.4 MB
  u16* xbf  = attn;                     // x bf16 — dead before flash writes attn
  u16* wT2  = (u16*)(ws + 33554432);    // w_out^T bf16 [1024][1024]  2.1 MB
  u16* wT1  = (u16*)(ws + 35651584);    // w_qkv^T bf16 [3072][1024]  6.3 MB
  u16* vT   = (u16*)(ws + 35651584);    // vT — overlaps wT1 (dead after GEMM1)

  prep<<<3072, 256, 0, stream>>>(w_qkv, w_out, x, wT1, wT2, xbf);
  gemm_bt<false, true ><<<dim3(24, 32), 256, 0, stream>>>(xbf, wT1, b_qkv, qkv,
                                                          4096, 3072, 1024, cosb, sinb);
  v_transpose<<<dim3(32, 32), 256, 0, stream>>>(qkv, vT);
  flash_attn<<<1024, 128, 0, stream>>>(qkv, vT, attn);
  gemm_bt<true , false><<<dim3(8, 32), 256, 0, stream>>>(attn, wT2, b_out, out,
                                                         4096, 1024, 1024, cosb, sinb);
}